// Round 1
// baseline (491.797 us; speedup 1.0000x reference)
//
#include <hip/hip_runtime.h>
#include <hip/hip_bf16.h>
#include <math.h>

// B=4, N=2048, DIM=1024, H=16, Dh=64.  out = proj(attn(x@Wqkv^T)) @ Wout^T
// All GEMMs bf16-MFMA (16x16x32) with fp32 accum; flash attention with
// online softmax. Workspace: bf16 casts of x/w + per-head q/k/v + attn out.

typedef __attribute__((ext_vector_type(8))) __bf16 bf16x8;
typedef __attribute__((ext_vector_type(8))) short short8;
typedef __attribute__((ext_vector_type(4))) float f32x4;
typedef unsigned short u16;
typedef unsigned int u32;

#define SEQ   2048
#define BATCH 4
#define DIM_  1024
#define NH    16
#define DH    64
#define MTOK  8192
#define QSCALE 0.125f

typedef unsigned int __attribute__((address_space(1))) u32_as1;
typedef unsigned int __attribute__((address_space(3))) u32_as3;

__device__ __forceinline__ void async16(void* lds, const void* g) {
  __builtin_amdgcn_global_load_lds((const u32_as1*)g, (u32_as3*)lds, 16, 0, 0);
}

__device__ __forceinline__ u16 f2bf(float f) {
  union { float f; u32 u; } a; a.f = f;
  u32 u = a.u;
  u = u + 0x7fffu + ((u >> 16) & 1u);   // RNE
  return (u16)(u >> 16);
}

__device__ __forceinline__ f32x4 mfma16(bf16x8 a, bf16x8 b, f32x4 c) {
  return __builtin_amdgcn_mfma_f32_16x16x32_bf16(a, b, c, 0, 0, 0);
}

// ---------------- cast fp32 -> bf16 ----------------
__global__ void cast_kernel(const float* __restrict__ in, u16* __restrict__ out, int n4) {
  int i = blockIdx.x * blockDim.x + threadIdx.x;
  if (i >= n4) return;
  float4 v = ((const float4*)in)[i];
  ushort4 o;
  o.x = f2bf(v.x); o.y = f2bf(v.y); o.z = f2bf(v.z); o.w = f2bf(v.w);
  ((ushort4*)out)[i] = o;
}

// ---------------- GEMM (bt): C[M][N] = A[M][K] * B[N][K]^T ----------------
// m97 structure: 128x128 tile, BK=32, 4 waves (2x2), 16 MFMA / K-step.
// MODE 0: qkv epilogue (scatter to per-head q/k/v bf16, q pre-scaled)
// MODE 1: fp32 epilogue to of[row*DIM_+col]
template<int MODE>
__global__ __launch_bounds__(256)
void gemm_bt(const u16* __restrict__ A, const u16* __restrict__ Bm, int K,
             u16* __restrict__ oq, u16* __restrict__ ok, u16* __restrict__ ov,
             float* __restrict__ of) {
  __shared__ __align__(16) u16 As[128*32];
  __shared__ __align__(16) u16 Bs[128*32];
  const int tid = threadIdx.x;
  const int l = tid & 63;
  const int w = tid >> 6;
  const int wr = w >> 1, wc = w & 1;
  const int bm = blockIdx.y, bn = blockIdx.x;

  f32x4 acc[4][4] = {};

  // staging: each wave covers 16 rows (1024B) per call, 2 calls per operand
  const int srow = w*16 + (l >> 2);
  const int scol = (l & 3) * 8;
  const u16* gA = A + (size_t)(bm*128 + srow) * K + scol;
  const u16* gB = Bm + (size_t)(bn*128 + srow) * K + scol;
  u16* lA0 = As + (w*16)*32;
  u16* lA1 = As + (w*16 + 64)*32;
  u16* lB0 = Bs + (w*16)*32;
  u16* lB1 = Bs + (w*16 + 64)*32;
  const size_t rstride = (size_t)64 * K;

  const int fA = (wr*64 + (l & 15))*32 + (l >> 4)*8;
  const int fB = (wc*64 + (l & 15))*32 + (l >> 4)*8;

  const int nk = K >> 5;
  for (int kk = 0; kk < nk; ++kk) {
    async16(lA0, gA);
    async16(lA1, gA + rstride);
    async16(lB0, gB);
    async16(lB1, gB + rstride);
    gA += 32; gB += 32;
    __syncthreads();
    bf16x8 af[4], bb[4];
#pragma unroll
    for (int m = 0; m < 4; ++m) af[m] = *(const bf16x8*)(As + fA + m*16*32);
#pragma unroll
    for (int n = 0; n < 4; ++n) bb[n] = *(const bf16x8*)(Bs + fB + n*16*32);
#pragma unroll
    for (int m = 0; m < 4; ++m)
#pragma unroll
      for (int n = 0; n < 4; ++n)
        acc[m][n] = mfma16(af[m], bb[n], acc[m][n]);
    __syncthreads();
  }

#pragma unroll
  for (int m = 0; m < 4; ++m) {
#pragma unroll
    for (int n = 0; n < 4; ++n) {
#pragma unroll
      for (int r = 0; r < 4; ++r) {
        float v = acc[m][n][r];
        int row = bm*128 + wr*64 + m*16 + (l >> 4)*4 + r;   // token index
        int col = bn*128 + wc*64 + n*16 + (l & 15);         // output feature
        if (MODE == 0) {
          int which = col >> 10;
          int rem = col & 1023;
          int h = rem >> 6, d = rem & 63;
          int b = row >> 11, nt = row & 2047;
          u16* dst = (which == 0) ? oq : (which == 1) ? ok : ov;
          float val = (which == 0) ? v * QSCALE : v;
          dst[((size_t)((b*NH + h)*SEQ + nt) << 6) + d] = f2bf(val);
        } else {
          of[(size_t)row * DIM_ + col] = v;
        }
      }
    }
  }
}

// ---------------- flash attention ----------------
// grid: x = SEQ/64 (q tiles), y = 64 (b*h). 256 threads = 4 waves x 16 q-rows.
// K tile [64][64] bf16 staged via global_load_lds with XOR swizzle
// (linear dest + inverse-swizzled global src; reads swizzle the chunk bits).
// V tile staged transposed into Vt[64][80] (pad 16 elems -> 4-way conflicts max).
// P round-trips through per-wave Pl[16][80].
__global__ __launch_bounds__(256)
void attn_kernel(const u16* __restrict__ Q, const u16* __restrict__ Kk,
                 const u16* __restrict__ V, u16* __restrict__ Ao) {
  __shared__ __align__(16) u16 Ks[64*64];
  __shared__ __align__(16) u16 Vt[64*80];
  __shared__ __align__(16) u16 Pl[4*16*80];
  const int tid = threadIdx.x;
  const int l = tid & 63, w = tid >> 6;
  const int lr = l & 15, lg = l >> 4;
  const int bh = blockIdx.y;
  const int q0 = blockIdx.x * 64;
  const size_t base = (size_t)bh * SEQ * DH;

  // Q fragments (16 rows x 64 cols per wave), q was pre-scaled by 1/sqrt(d)
  bf16x8 aq0 = *(const bf16x8*)(Q + base + (size_t)(q0 + w*16 + lr)*DH + lg*8);
  bf16x8 aq1 = *(const bf16x8*)(Q + base + (size_t)(q0 + w*16 + lr)*DH + 32 + lg*8);

  float m_run[4], l_run[4];
  f32x4 o[4] = {};
#pragma unroll
  for (int r = 0; r < 4; ++r) { m_run[r] = -INFINITY; l_run[r] = 0.f; }

  // K staging addresses: wave w covers rows [w*8, w*8+8) (+32 second call)
  const int krow = l >> 3;                 // row within wave region
  const int kc   = (l & 7) ^ krow;         // inverse-swizzled global chunk
  const u16* gK = Kk + base + (size_t)(w*8 + krow)*DH + kc*8;
  u16* lK0 = Ks + (w*8)*64;
  u16* lK1 = Ks + (32 + w*8)*64;
  u16* Pw = Pl + w*16*80;

  for (int kt = 0; kt < SEQ/64; ++kt) {
    const u16* gKt = gK + (size_t)kt*64*DH;
    async16(lK0, gKt);
    async16(lK1, gKt + 32*DH);
    // V transpose stage: 256 threads x 2 x 8 elems
#pragma unroll
    for (int it = 0; it < 2; ++it) {
      int idx = tid + it*256;
      int key = idx >> 3, c = idx & 7;
      short8 v8 = *(const short8*)(V + base + (size_t)(kt*64 + key)*DH + c*8);
#pragma unroll
      for (int j = 0; j < 8; ++j)
        Vt[(c*8 + j)*80 + key] = (u16)v8[j];
    }
    __syncthreads();

    // S = Q K^T for 16 q-rows x 64 keys
    f32x4 s[4];
#pragma unroll
    for (int t = 0; t < 4; ++t) {
      int row = t*16 + lr;
      const char* kb = (const char*)Ks + row*128;
      int sw = (row & 7) << 4;
      bf16x8 b0 = *(const bf16x8*)(kb + ((lg*16) ^ sw));
      bf16x8 b1 = *(const bf16x8*)(kb + ((64 + lg*16) ^ sw));
      f32x4 sv = {};
      sv = mfma16(aq0, b0, sv);
      sv = mfma16(aq1, b1, sv);
      s[t] = sv;
    }

    // online softmax (row r held by all 16 lanes of group lg; reduce over lr)
#pragma unroll
    for (int r = 0; r < 4; ++r) {
      float mm = fmaxf(fmaxf(s[0][r], s[1][r]), fmaxf(s[2][r], s[3][r]));
      mm = fmaxf(mm, __shfl_xor(mm, 1));
      mm = fmaxf(mm, __shfl_xor(mm, 2));
      mm = fmaxf(mm, __shfl_xor(mm, 4));
      mm = fmaxf(mm, __shfl_xor(mm, 8));
      float mn = fmaxf(m_run[r], mm);
      float sc_ = __expf(m_run[r] - mn);
      m_run[r] = mn;
      float su = 0.f;
#pragma unroll
      for (int t = 0; t < 4; ++t) {
        float pv = __expf(s[t][r] - mn);
        su += pv;
        Pw[(lg*4 + r)*80 + t*16 + lr] = f2bf(pv);
      }
      su += __shfl_xor(su, 1);
      su += __shfl_xor(su, 2);
      su += __shfl_xor(su, 4);
      su += __shfl_xor(su, 8);
      l_run[r] = l_run[r]*sc_ + su;
#pragma unroll
      for (int dt = 0; dt < 4; ++dt) o[dt][r] *= sc_;
    }

    // O += P V  (A from Pl, B from Vt)
    bf16x8 pa0 = *(const bf16x8*)(Pw + lr*80 + lg*8);
    bf16x8 pa1 = *(const bf16x8*)(Pw + lr*80 + 32 + lg*8);
#pragma unroll
    for (int dt = 0; dt < 4; ++dt) {
      bf16x8 bv0 = *(const bf16x8*)(Vt + (dt*16 + lr)*80 + lg*8);
      bf16x8 bv1 = *(const bf16x8*)(Vt + (dt*16 + lr)*80 + 32 + lg*8);
      o[dt] = mfma16(pa0, bv0, o[dt]);
      o[dt] = mfma16(pa1, bv1, o[dt]);
    }
    __syncthreads();
  }

  const int b = bh >> 4, h = bh & 15;
#pragma unroll
  for (int dt = 0; dt < 4; ++dt) {
#pragma unroll
    for (int r = 0; r < 4; ++r) {
      int qq = q0 + w*16 + lg*4 + r;
      int col = h*64 + dt*16 + lr;
      Ao[(size_t)(b*SEQ + qq)*DIM_ + col] = f2bf(o[dt][r] / l_run[r]);
    }
  }
}

// ---------------- launch ----------------
extern "C" void kernel_launch(void* const* d_in, const int* in_sizes, int n_in,
                              void* d_out, int out_size, void* d_ws, size_t ws_size,
                              hipStream_t stream) {
  const float* x    = (const float*)d_in[0];
  const float* wqkv = (const float*)d_in[1];
  const float* wout = (const float*)d_in[2];
  float* out = (float*)d_out;
  char* ws = (char*)d_ws;

  u16* x_bf    = (u16*)(ws + 0);            // 8192*1024*2  = 16777216
  u16* wqkv_bf = (u16*)(ws + 16777216);     // 3072*1024*2  =  6291456
  u16* wout_bf = (u16*)(ws + 23068672);     // 1024*1024*2  =  2097152
  u16* q_bf    = (u16*)(ws + 25165824);     // 64*2048*64*2 = 16777216
  u16* k_bf    = (u16*)(ws + 41943040);
  u16* v_bf    = (u16*)(ws + 58720256);
  u16* a_bf    = (u16*)(ws + 75497472);     // attn out, [b][n][dim] bf16
  // total ws use: 92274688 bytes

  cast_kernel<<<dim3(MTOK*DIM_/4/256), 256, 0, stream>>>(x, x_bf, MTOK*DIM_/4);
  cast_kernel<<<dim3(3*DIM_*DIM_/4/256), 256, 0, stream>>>(wqkv, wqkv_bf, 3*DIM_*DIM_/4);
  cast_kernel<<<dim3(DIM_*DIM_/4/256), 256, 0, stream>>>(wout, wout_bf, DIM_*DIM_/4);

  gemm_bt<0><<<dim3(3*DIM_/128, MTOK/128), 256, 0, stream>>>(
      x_bf, wqkv_bf, DIM_, q_bf, k_bf, v_bf, nullptr);
  attn_kernel<<<dim3(SEQ/64, BATCH*NH), 256, 0, stream>>>(q_bf, k_bf, v_bf, a_bf);
  gemm_bt<1><<<dim3(DIM_/128, MTOK/128), 256, 0, stream>>>(
      a_bf, wout_bf, DIM_, nullptr, nullptr, nullptr, out);
}

// Round 8
// 404.927 us; speedup vs baseline: 1.2145x; 1.2145x over previous
//
#include <hip/hip_runtime.h>
#include <hip/hip_bf16.h>
#include <math.h>

// B=4, N=2048, DIM=1024, H=16, Dh=64.  out = proj(attn(x@Wqkv^T)) @ Wout^T
// bf16 MFMA (16x16x32) everywhere, fp32 accum. Flash attention, online softmax.
// R2: V stored transposed [bh][d][n] by GEMM1 epilogue -> attn stages K and V
// identically (global_load_lds + XOR swizzle, rule #21); P buffer XOR-swizzled
// stride-64; K/V double-buffered, 1 barrier/tile, stage issued after barrier.

typedef __attribute__((ext_vector_type(8))) __bf16 bf16x8;
typedef __attribute__((ext_vector_type(4))) float f32x4;
typedef unsigned short u16;
typedef unsigned int u32;

#define SEQ   2048
#define BATCH 4
#define DIM_  1024
#define NH    16
#define DH    64
#define MTOK  8192
#define QSCALE 0.125f

typedef unsigned int __attribute__((address_space(1))) u32_as1;
typedef unsigned int __attribute__((address_space(3))) u32_as3;

__device__ __forceinline__ void async16(void* lds, const void* g) {
  __builtin_amdgcn_global_load_lds((const u32_as1*)g, (u32_as3*)lds, 16, 0, 0);
}

__device__ __forceinline__ u16 f2bf(float f) {
  union { float f; u32 u; } a; a.f = f;
  u32 u = a.u;
  u = u + 0x7fffu + ((u >> 16) & 1u);   // RNE
  return (u16)(u >> 16);
}

__device__ __forceinline__ f32x4 mfma16(bf16x8 a, bf16x8 b, f32x4 c) {
  return __builtin_amdgcn_mfma_f32_16x16x32_bf16(a, b, c, 0, 0, 0);
}

// ---------------- cast fp32 -> bf16 ----------------
__global__ void cast_kernel(const float* __restrict__ in, u16* __restrict__ out, int n4) {
  int i = blockIdx.x * blockDim.x + threadIdx.x;
  if (i >= n4) return;
  float4 v = ((const float4*)in)[i];
  ushort4 o;
  o.x = f2bf(v.x); o.y = f2bf(v.y); o.z = f2bf(v.z); o.w = f2bf(v.w);
  ((ushort4*)out)[i] = o;
}

// ---------------- GEMM (bt): C[M][N] = A[M][K] * B[N][K]^T ----------------
// 128x128 tile, BK=32, 4 waves (2x2), 16 MFMA / K-step (m97 structure).
// MODE 0: qkv epilogue -> q,k as [bh][n][64] bf16 (q pre-scaled), v as [bh][64][n]
// MODE 1: fp32 epilogue to of[row*DIM_+col]
template<int MODE>
__global__ __launch_bounds__(256)
void gemm_bt(const u16* __restrict__ A, const u16* __restrict__ Bm, int K,
             u16* __restrict__ oq, u16* __restrict__ ok, u16* __restrict__ ov,
             float* __restrict__ of) {
  __shared__ __align__(16) u16 As[128*32];
  __shared__ __align__(16) u16 Bs[128*32];
  const int tid = threadIdx.x;
  const int l = tid & 63;
  const int w = tid >> 6;
  const int wr = w >> 1, wc = w & 1;
  const int lr = l & 15, lg = l >> 4;
  const int bm = blockIdx.y, bn = blockIdx.x;

  f32x4 acc[4][4] = {};

  const int srow = w*16 + (l >> 2);
  const int scol = (l & 3) * 8;
  const u16* gA = A + (size_t)(bm*128 + srow) * K + scol;
  const u16* gB = Bm + (size_t)(bn*128 + srow) * K + scol;
  u16* lA0 = As + (w*16)*32;
  u16* lA1 = As + (w*16 + 64)*32;
  u16* lB0 = Bs + (w*16)*32;
  u16* lB1 = Bs + (w*16 + 64)*32;
  const size_t rstride = (size_t)64 * K;

  const int fA = (wr*64 + lr)*32 + lg*8;
  const int fB = (wc*64 + lr)*32 + lg*8;

  const int nk = K >> 5;
  for (int kk = 0; kk < nk; ++kk) {
    async16(lA0, gA);
    async16(lA1, gA + rstride);
    async16(lB0, gB);
    async16(lB1, gB + rstride);
    gA += 32; gB += 32;
    __syncthreads();
    bf16x8 af[4], bb[4];
#pragma unroll
    for (int m = 0; m < 4; ++m) af[m] = *(const bf16x8*)(As + fA + m*16*32);
#pragma unroll
    for (int n = 0; n < 4; ++n) bb[n] = *(const bf16x8*)(Bs + fB + n*16*32);
#pragma unroll
    for (int m = 0; m < 4; ++m)
#pragma unroll
      for (int n = 0; n < 4; ++n)
        acc[m][n] = mfma16(af[m], bb[n], acc[m][n]);
    __syncthreads();
  }

#pragma unroll
  for (int m = 0; m < 4; ++m) {
    const int row0 = bm*128 + wr*64 + m*16 + lg*4;   // token base for this lane
    const int b = row0 >> 11, nt0 = row0 & 2047;
#pragma unroll
    for (int n = 0; n < 4; ++n) {
      const int col = bn*128 + wc*64 + n*16 + lr;
      if (MODE == 1) {
#pragma unroll
        for (int r = 0; r < 4; ++r)
          of[(size_t)(row0 + r) * DIM_ + col] = acc[m][n][r];
      } else {
        const int which = col >> 10;       // uniform within block
        const int rem = col & 1023;
        const int h = rem >> 6, d = rem & 63;
        if (which == 2) {
          // V^T layout: [bh][d][n]; lane's 4 r-values are consecutive tokens
          u32 p0 = (u32)f2bf(acc[m][n][0]) | ((u32)f2bf(acc[m][n][1]) << 16);
          u32 p1 = (u32)f2bf(acc[m][n][2]) | ((u32)f2bf(acc[m][n][3]) << 16);
          uint2 val; val.x = p0; val.y = p1;
          *(uint2*)(ov + ((size_t)((b*NH + h)*DH + d)) * SEQ + nt0) = val;
        } else {
          u16* dst = (which == 0) ? oq : ok;
          const float sc = (which == 0) ? QSCALE : 1.f;
#pragma unroll
          for (int r = 0; r < 4; ++r)
            dst[((size_t)((b*NH + h)*SEQ + nt0 + r) << 6) + d] = f2bf(acc[m][n][r] * sc);
        }
      }
    }
  }
}

// ---------------- flash attention ----------------
// grid: x = SEQ/64 (q tiles), y = 64 (b*h). 256 threads = 4 waves x 16 q-rows.
// K [bh][n][64] and Vt [bh][64][n] both staged via global_load_lds into
// XOR-swizzled [64][64] tiles (linear dest + inverse-swizzled global src).
// Double-buffered; one barrier per tile; stage issued after barrier so the
// loads overlap compute. P round-trips through per-wave XOR-swizzled [16][64].
__global__ __launch_bounds__(256)
void attn_kernel(const u16* __restrict__ Q, const u16* __restrict__ Kk,
                 const u16* __restrict__ Vt, u16* __restrict__ Ao) {
  __shared__ __align__(16) u16 KsB[2][64*64];
  __shared__ __align__(16) u16 VsB[2][64*64];
  __shared__ __align__(16) u16 Pl[4*16*64];
  const int tid = threadIdx.x;
  const int l = tid & 63, w = tid >> 6;
  const int lr = l & 15, lg = l >> 4;
  const int bh = blockIdx.y;
  const int q0 = blockIdx.x * 64;
  const size_t base = (size_t)bh * SEQ * DH;

  // Q fragments (16 rows x 64 cols per wave), q pre-scaled by 1/sqrt(d)
  bf16x8 aq0 = *(const bf16x8*)(Q + base + (size_t)(q0 + w*16 + lr)*DH + lg*8);
  bf16x8 aq1 = *(const bf16x8*)(Q + base + (size_t)(q0 + w*16 + lr)*DH + 32 + lg*8);

  float m_run[4], l_run[4];
  f32x4 o[4] = {};
#pragma unroll
  for (int r = 0; r < 4; ++r) { m_run[r] = -INFINITY; l_run[r] = 0.f; }

  // staging addresses (both-sides swizzle: inverse-swizzled global source)
  const int srow = l >> 3;                  // row within wave's 8-row region
  const int sch  = (l & 7) ^ srow;          // inverse-swizzled global chunk
  const u16* gK  = Kk + base + (size_t)(w*8 + srow)*DH + sch*8;
  const u16* gV  = Vt + base + (size_t)(w*8 + srow)*SEQ + sch*8;
  u16* Pw = Pl + w*16*64;

  const int NT = SEQ/64;
#define STAGE(bs, kt)                                            \
  do {                                                           \
    const u16* gKt_ = gK + (size_t)(kt)*64*DH;                   \
    async16(KsB[bs] + (w*8)*64, gKt_);                           \
    async16(KsB[bs] + (32 + w*8)*64, gKt_ + 32*DH);              \
    const u16* gVt_ = gV + (size_t)(kt)*64;                      \
    async16(VsB[bs] + (w*8)*64, gVt_);                           \
    async16(VsB[bs] + (32 + w*8)*64, gVt_ + (size_t)32*SEQ);     \
  } while (0)

  STAGE(0, 0);
  for (int kt = 0; kt < NT; ++kt) {
    const int cur = kt & 1;
    __syncthreads();                       // cur tile ready (drains vmcnt)
    if (kt + 1 < NT) STAGE(cur ^ 1, kt + 1);

    const u16* Ks = KsB[cur];
    const u16* Vs = VsB[cur];

    // S = Q K^T for 16 q-rows x 64 keys
    f32x4 s[4];
#pragma unroll
    for (int t = 0; t < 4; ++t) {
      const int row = t*16 + lr;
      const char* kb = (const char*)Ks + row*128;
      const int sw = (row & 7) << 4;
      bf16x8 b0 = *(const bf16x8*)(kb + ((lg*16) ^ sw));
      bf16x8 b1 = *(const bf16x8*)(kb + ((64 + lg*16) ^ sw));
      f32x4 sv = {};
      sv = mfma16(aq0, b0, sv);
      sv = mfma16(aq1, b1, sv);
      s[t] = sv;
    }

    // online softmax (row q = lg*4+r spread over 16 lanes lr)
#pragma unroll
    for (int r = 0; r < 4; ++r) {
      float mm = fmaxf(fmaxf(s[0][r], s[1][r]), fmaxf(s[2][r], s[3][r]));
      mm = fmaxf(mm, __shfl_xor(mm, 1));
      mm = fmaxf(mm, __shfl_xor(mm, 2));
      mm = fmaxf(mm, __shfl_xor(mm, 4));
      mm = fmaxf(mm, __shfl_xor(mm, 8));
      const float mn = fmaxf(m_run[r], mm);
      const float sc_ = __expf(m_run[r] - mn);
      m_run[r] = mn;
      const int q = lg*4 + r;
      float su = 0.f;
#pragma unroll
      for (int t = 0; t < 4; ++t) {
        float pv = __expf(s[t][r] - mn);
        su += pv;
        const int k = t*16 + lr;
        *(u16*)((char*)Pw + q*128 + ((((k >> 3) ^ (q & 7)) << 4) | ((k & 7) << 1))) = f2bf(pv);
      }
      su += __shfl_xor(su, 1);
      su += __shfl_xor(su, 2);
      su += __shfl_xor(su, 4);
      su += __shfl_xor(su, 8);
      l_run[r] = l_run[r]*sc_ + su;
#pragma unroll
      for (int dt = 0; dt < 4; ++dt) o[dt][r] *= sc_;
    }

    // O += P V   (A from swizzled Pw, B from swizzled Vs rows = V^T rows)
    const char* Pb = (const char*)Pw + lr*128;
    const int swp = (lr & 7) << 4;
    bf16x8 pa0 = *(const bf16x8*)(Pb + ((lg*16) ^ swp));
    bf16x8 pa1 = *(const bf16x8*)(Pb + ((64 + lg*16) ^ swp));
#pragma unroll
    for (int dt = 0; dt < 4; ++dt) {
      const int rowv = dt*16 + lr;
      const char* vb = (const char*)Vs + rowv*128;
      const int swv = (rowv & 7) << 4;
      bf16x8 bv0 = *(const bf16x8*)(vb + ((lg*16) ^ swv));
      bf16x8 bv1 = *(const bf16x8*)(vb + ((64 + lg*16) ^ swv));
      o[dt] = mfma16(pa0, bv0, o[dt]);
      o[dt] = mfma16(pa1, bv1, o[dt]);
    }
  }
#undef STAGE

  const int b = bh >> 4, h = bh & 15;
#pragma unroll
  for (int dt = 0; dt < 4; ++dt) {
#pragma unroll
    for (int r = 0; r < 4; ++r) {
      const int qq = q0 + w*16 + lg*4 + r;
      const int col = h*64 + dt*16 + lr;
      Ao[(size_t)(b*SEQ + qq)*DIM_ + col] = f2bf(o[dt][r] / l_run[r]);
    }
  }
}

// ---------------- launch ----------------
extern "C" void kernel_launch(void* const* d_in, const int* in_sizes, int n_in,
                              void* d_out, int out_size, void* d_ws, size_t ws_size,
                              hipStream_t stream) {
  const float* x    = (const float*)d_in[0];
  const float* wqkv = (const float*)d_in[1];
  const float* wout = (const float*)d_in[2];
  float* out = (float*)d_out;
  char* ws = (char*)d_ws;

  u16* x_bf    = (u16*)(ws + 0);            // 8192*1024*2  = 16777216
  u16* wqkv_bf = (u16*)(ws + 16777216);     // 3072*1024*2  =  6291456
  u16* wout_bf = (u16*)(ws + 23068672);     // 1024*1024*2  =  2097152
  u16* q_bf    = (u16*)(ws + 25165824);     // 64*2048*64*2 = 16777216
  u16* k_bf    = (u16*)(ws + 41943040);
  u16* vt_bf   = (u16*)(ws + 58720256);     // V^T: [bh][64][2048]
  u16* a_bf    = (u16*)(ws + 75497472);     // attn out, [b][n][dim] bf16

  cast_kernel<<<dim3(MTOK*DIM_/4/256), 256, 0, stream>>>(x, x_bf, MTOK*DIM_/4);
  cast_kernel<<<dim3(3*DIM_*DIM_/4/256), 256, 0, stream>>>(wqkv, wqkv_bf, 3*DIM_*DIM_/4);
  cast_kernel<<<dim3(DIM_*DIM_/4/256), 256, 0, stream>>>(wout, wout_bf, DIM_*DIM_/4);

  gemm_bt<0><<<dim3(3*DIM_/128, MTOK/128), 256, 0, stream>>>(
      x_bf, wqkv_bf, DIM_, q_bf, k_bf, vt_bf, nullptr);
  attn_kernel<<<dim3(SEQ/64, BATCH*NH), 256, 0, stream>>>(q_bf, k_bf, vt_bf, a_bf);
  gemm_bt<1><<<dim3(DIM_/128, MTOK/128), 256, 0, stream>>>(
      a_bf, wout_bf, DIM_, nullptr, nullptr, nullptr, out);
}

// Round 9
// 362.016 us; speedup vs baseline: 1.3585x; 1.1185x over previous
//
#include <hip/hip_runtime.h>
#include <hip/hip_bf16.h>
#include <math.h>

// B=4, N=2048, DIM=1024, H=16, Dh=64.  out = proj(attn(x@Wqkv^T)) @ Wout^T
// bf16 MFMA (16x16x32), fp32 accum. Flash attention, online softmax.
// R8: VALU-cut round. (1) softmax in exp2 domain (log2e folded into Q scale);
// (2) defer-max THR=8 skips o/l rescale on most tiles; (3) P->bf16 via
// v_cvt_pk_bf16_f32; (4) row sums via ones-MFMA (replaces 16 shfl+16 add/tile).

typedef __attribute__((ext_vector_type(8))) __bf16 bf16x8;
typedef __attribute__((ext_vector_type(4))) float f32x4;
typedef unsigned short u16;
typedef unsigned int u32;

#define SEQ   2048
#define BATCH 4
#define DIM_  1024
#define NH    16
#define DH    64
#define MTOK  8192
// 1/sqrt(64) * log2(e): softmax computed as 2^(s - m)
#define QSCALE_L2E 0.180336880f

typedef unsigned int __attribute__((address_space(1))) u32_as1;
typedef unsigned int __attribute__((address_space(3))) u32_as3;

__device__ __forceinline__ void async16(void* lds, const void* g) {
  __builtin_amdgcn_global_load_lds((const u32_as1*)g, (u32_as3*)lds, 16, 0, 0);
}

__device__ __forceinline__ u16 f2bf(float f) {
  union { float f; u32 u; } a; a.f = f;
  u32 u = a.u;
  u = u + 0x7fffu + ((u >> 16) & 1u);   // RNE
  return (u16)(u >> 16);
}

__device__ __forceinline__ float fexp2(float x) {
#if __has_builtin(__builtin_amdgcn_exp2f)
  return __builtin_amdgcn_exp2f(x);
#else
  return exp2f(x);
#endif
}

__device__ __forceinline__ u32 cvtpk(float lo, float hi) {
  u32 r;
  asm("v_cvt_pk_bf16_f32 %0, %1, %2" : "=v"(r) : "v"(lo), "v"(hi));
  return r;
}

__device__ __forceinline__ f32x4 mfma16(bf16x8 a, bf16x8 b, f32x4 c) {
  return __builtin_amdgcn_mfma_f32_16x16x32_bf16(a, b, c, 0, 0, 0);
}

// ---------------- cast fp32 -> bf16 ----------------
__global__ void cast_kernel(const float* __restrict__ in, u16* __restrict__ out, int n4) {
  int i = blockIdx.x * blockDim.x + threadIdx.x;
  if (i >= n4) return;
  float4 v = ((const float4*)in)[i];
  ushort4 o;
  o.x = f2bf(v.x); o.y = f2bf(v.y); o.z = f2bf(v.z); o.w = f2bf(v.w);
  ((ushort4*)out)[i] = o;
}

// ---------------- GEMM (bt): C[M][N] = A[M][K] * B[N][K]^T ----------------
// 128x128 tile, BK=32, 4 waves (2x2), 16 MFMA / K-step (m97 structure).
// MODE 0: qkv epilogue -> q,k as [bh][n][64] bf16 (q scaled by 1/8*log2e),
//         v as [bh][64][n] (transposed)
// MODE 1: fp32 epilogue to of[row*DIM_+col]
template<int MODE>
__global__ __launch_bounds__(256)
void gemm_bt(const u16* __restrict__ A, const u16* __restrict__ Bm, int K,
             u16* __restrict__ oq, u16* __restrict__ ok, u16* __restrict__ ov,
             float* __restrict__ of) {
  __shared__ __align__(16) u16 As[128*32];
  __shared__ __align__(16) u16 Bs[128*32];
  const int tid = threadIdx.x;
  const int l = tid & 63;
  const int w = tid >> 6;
  const int wr = w >> 1, wc = w & 1;
  const int lr = l & 15, lg = l >> 4;
  const int bm = blockIdx.y, bn = blockIdx.x;

  f32x4 acc[4][4] = {};

  const int srow = w*16 + (l >> 2);
  const int scol = (l & 3) * 8;
  const u16* gA = A + (size_t)(bm*128 + srow) * K + scol;
  const u16* gB = Bm + (size_t)(bn*128 + srow) * K + scol;
  u16* lA0 = As + (w*16)*32;
  u16* lA1 = As + (w*16 + 64)*32;
  u16* lB0 = Bs + (w*16)*32;
  u16* lB1 = Bs + (w*16 + 64)*32;
  const size_t rstride = (size_t)64 * K;

  const int fA = (wr*64 + lr)*32 + lg*8;
  const int fB = (wc*64 + lr)*32 + lg*8;

  const int nk = K >> 5;
  for (int kk = 0; kk < nk; ++kk) {
    async16(lA0, gA);
    async16(lA1, gA + rstride);
    async16(lB0, gB);
    async16(lB1, gB + rstride);
    gA += 32; gB += 32;
    __syncthreads();
    bf16x8 af[4], bb[4];
#pragma unroll
    for (int m = 0; m < 4; ++m) af[m] = *(const bf16x8*)(As + fA + m*16*32);
#pragma unroll
    for (int n = 0; n < 4; ++n) bb[n] = *(const bf16x8*)(Bs + fB + n*16*32);
#pragma unroll
    for (int m = 0; m < 4; ++m)
#pragma unroll
      for (int n = 0; n < 4; ++n)
        acc[m][n] = mfma16(af[m], bb[n], acc[m][n]);
    __syncthreads();
  }

#pragma unroll
  for (int m = 0; m < 4; ++m) {
    const int row0 = bm*128 + wr*64 + m*16 + lg*4;   // token base for this lane
    const int b = row0 >> 11, nt0 = row0 & 2047;
#pragma unroll
    for (int n = 0; n < 4; ++n) {
      const int col = bn*128 + wc*64 + n*16 + lr;
      if (MODE == 1) {
#pragma unroll
        for (int r = 0; r < 4; ++r)
          of[(size_t)(row0 + r) * DIM_ + col] = acc[m][n][r];
      } else {
        const int which = col >> 10;       // uniform within block
        const int rem = col & 1023;
        const int h = rem >> 6, d = rem & 63;
        if (which == 2) {
          // V^T layout: [bh][d][n]; lane's 4 r-values are consecutive tokens
          u32 p0 = (u32)f2bf(acc[m][n][0]) | ((u32)f2bf(acc[m][n][1]) << 16);
          u32 p1 = (u32)f2bf(acc[m][n][2]) | ((u32)f2bf(acc[m][n][3]) << 16);
          uint2 val; val.x = p0; val.y = p1;
          *(uint2*)(ov + ((size_t)((b*NH + h)*DH + d)) * SEQ + nt0) = val;
        } else {
          u16* dst = (which == 0) ? oq : ok;
          const float sc = (which == 0) ? QSCALE_L2E : 1.f;
#pragma unroll
          for (int r = 0; r < 4; ++r)
            dst[((size_t)((b*NH + h)*SEQ + nt0 + r) << 6) + d] = f2bf(acc[m][n][r] * sc);
        }
      }
    }
  }
}

// ---------------- flash attention ----------------
// grid: x = SEQ/64 (q tiles), y = 64 (b*h). 256 threads = 4 waves x 16 q-rows.
// K [bh][n][64] and Vt [bh][64][n] both staged via global_load_lds into
// XOR-swizzled [64][64] tiles (linear dest + inverse-swizzled global src).
// Double-buffered; one barrier per tile; stage issued after barrier.
// Softmax in exp2 domain with defer-max; P round-trips through per-wave
// XOR-swizzled [16][64]; row sums l via ones-MFMA on the P fragments.
__global__ __launch_bounds__(256)
void attn_kernel(const u16* __restrict__ Q, const u16* __restrict__ Kk,
                 const u16* __restrict__ Vt, u16* __restrict__ Ao) {
  __shared__ __align__(16) u16 KsB[2][64*64];
  __shared__ __align__(16) u16 VsB[2][64*64];
  __shared__ __align__(16) u16 Pl[4*16*64];
  const int tid = threadIdx.x;
  const int l = tid & 63, w = tid >> 6;
  const int lr = l & 15, lg = l >> 4;
  const int bh = blockIdx.y;
  const int q0 = blockIdx.x * 64;
  const size_t base = (size_t)bh * SEQ * DH;

  // Q fragments (16 rows x 64 cols per wave); q pre-scaled by 1/8*log2e
  bf16x8 aq0 = *(const bf16x8*)(Q + base + (size_t)(q0 + w*16 + lr)*DH + lg*8);
  bf16x8 aq1 = *(const bf16x8*)(Q + base + (size_t)(q0 + w*16 + lr)*DH + 32 + lg*8);

  bf16x8 ones;
#pragma unroll
  for (int j = 0; j < 8; ++j) ones[j] = (__bf16)1.0f;

  float m_run[4], l_run[4];
  f32x4 o[4] = {};
#pragma unroll
  for (int r = 0; r < 4; ++r) { m_run[r] = -INFINITY; l_run[r] = 0.f; }

  // staging addresses (both-sides swizzle: inverse-swizzled global source)
  const int srow = l >> 3;                  // row within wave's 8-row region
  const int sch  = (l & 7) ^ srow;          // inverse-swizzled global chunk
  const u16* gK  = Kk + base + (size_t)(w*8 + srow)*DH + sch*8;
  const u16* gV  = Vt + base + (size_t)(w*8 + srow)*SEQ + sch*8;
  u16* Pw = Pl + w*16*64;

  const int NT = SEQ/64;
#define STAGE(bs, kt)                                            \
  do {                                                           \
    const u16* gKt_ = gK + (size_t)(kt)*64*DH;                   \
    async16(KsB[bs] + (w*8)*64, gKt_);                           \
    async16(KsB[bs] + (32 + w*8)*64, gKt_ + 32*DH);              \
    const u16* gVt_ = gV + (size_t)(kt)*64;                      \
    async16(VsB[bs] + (w*8)*64, gVt_);                           \
    async16(VsB[bs] + (32 + w*8)*64, gVt_ + (size_t)32*SEQ);     \
  } while (0)

  STAGE(0, 0);
  for (int kt = 0; kt < NT; ++kt) {
    const int cur = kt & 1;
    __syncthreads();                       // cur tile ready (drains vmcnt)
    if (kt + 1 < NT) STAGE(cur ^ 1, kt + 1);

    const u16* Ks = KsB[cur];
    const u16* Vs = VsB[cur];

    // S = Q K^T for 16 q-rows x 64 keys (log2-scaled)
    f32x4 s[4];
#pragma unroll
    for (int t = 0; t < 4; ++t) {
      const int row = t*16 + lr;
      const char* kb = (const char*)Ks + row*128;
      const int sw = (row & 7) << 4;
      bf16x8 b0 = *(const bf16x8*)(kb + ((lg*16) ^ sw));
      bf16x8 b1 = *(const bf16x8*)(kb + ((64 + lg*16) ^ sw));
      f32x4 sv = {};
      sv = mfma16(aq0, b0, sv);
      sv = mfma16(aq1, b1, sv);
      s[t] = sv;
    }

    // row max (uniform across the 16 lanes of each group) + defer-max
    float mm[4];
    bool need = false;
#pragma unroll
    for (int r = 0; r < 4; ++r) {
      float v = fmaxf(fmaxf(s[0][r], s[1][r]), fmaxf(s[2][r], s[3][r]));
      v = fmaxf(v, __shfl_xor(v, 1));
      v = fmaxf(v, __shfl_xor(v, 2));
      v = fmaxf(v, __shfl_xor(v, 4));
      v = fmaxf(v, __shfl_xor(v, 8));
      mm[r] = v;
      need = need || (v > m_run[r] + 8.f);
    }
    if (__any(need)) {                     // rescale only when max grew >2^8
#pragma unroll
      for (int r = 0; r < 4; ++r) {
        const float mn = fmaxf(m_run[r], mm[r]);
        const float sc_ = fexp2(m_run[r] - mn);
        m_run[r] = mn;
        l_run[r] *= sc_;
#pragma unroll
        for (int dt = 0; dt < 4; ++dt) o[dt][r] *= sc_;
      }
    }

    // P = 2^(s - m) -> bf16 via cvt_pk, swizzled store
#pragma unroll
    for (int r = 0; r < 4; ++r) {
      const int q = lg*4 + r;
      char* basep = (char*)Pw + q*128;
      const int sq = q & 7;
      const int h0 = lr >> 3, lo = (lr & 7) << 1;
      float p0 = fexp2(s[0][r] - m_run[r]);
      float p1 = fexp2(s[1][r] - m_run[r]);
      float p2 = fexp2(s[2][r] - m_run[r]);
      float p3 = fexp2(s[3][r] - m_run[r]);
      u32 a01 = cvtpk(p0, p1);
      u32 a23 = cvtpk(p2, p3);
      *(u16*)(basep + ((((0 + h0) ^ sq) << 4) | lo)) = (u16)a01;
      *(u16*)(basep + ((((2 + h0) ^ sq) << 4) | lo)) = (u16)(a01 >> 16);
      *(u16*)(basep + ((((4 + h0) ^ sq) << 4) | lo)) = (u16)a23;
      *(u16*)(basep + ((((6 + h0) ^ sq) << 4) | lo)) = (u16)(a23 >> 16);
    }

    // P fragments; row sums via ones-MFMA (D layout row=lg*4+r matches l_run)
    const char* Pb = (const char*)Pw + lr*128;
    const int swp = (lr & 7) << 4;
    bf16x8 pa0 = *(const bf16x8*)(Pb + ((lg*16) ^ swp));
    bf16x8 pa1 = *(const bf16x8*)(Pb + ((64 + lg*16) ^ swp));
    f32x4 osum = {};
    osum = mfma16(pa0, ones, osum);
    osum = mfma16(pa1, ones, osum);
#pragma unroll
    for (int r = 0; r < 4; ++r) l_run[r] += osum[r];

    // O += P V   (B from swizzled Vs rows = V^T rows)
#pragma unroll
    for (int dt = 0; dt < 4; ++dt) {
      const int rowv = dt*16 + lr;
      const char* vb = (const char*)Vs + rowv*128;
      const int swv = (rowv & 7) << 4;
      bf16x8 bv0 = *(const bf16x8*)(vb + ((lg*16) ^ swv));
      bf16x8 bv1 = *(const bf16x8*)(vb + ((64 + lg*16) ^ swv));
      o[dt] = mfma16(pa0, bv0, o[dt]);
      o[dt] = mfma16(pa1, bv1, o[dt]);
    }
  }
#undef STAGE

  const int b = bh >> 4, h = bh & 15;
#pragma unroll
  for (int dt = 0; dt < 4; ++dt) {
#pragma unroll
    for (int r = 0; r < 4; ++r) {
      const int qq = q0 + w*16 + lg*4 + r;
      const int col = h*64 + dt*16 + lr;
      Ao[(size_t)(b*SEQ + qq)*DIM_ + col] = f2bf(o[dt][r] / l_run[r]);
    }
  }
}

// ---------------- launch ----------------
extern "C" void kernel_launch(void* const* d_in, const int* in_sizes, int n_in,
                              void* d_out, int out_size, void* d_ws, size_t ws_size,
                              hipStream_t stream) {
  const float* x    = (const float*)d_in[0];
  const float* wqkv = (const float*)d_in[1];
  const float* wout = (const float*)d_in[2];
  float* out = (float*)d_out;
  char* ws = (char*)d_ws;

  u16* x_bf    = (u16*)(ws + 0);            // 8192*1024*2  = 16777216
  u16* wqkv_bf = (u16*)(ws + 16777216);     // 3072*1024*2  =  6291456
  u16* wout_bf = (u16*)(ws + 23068672);     // 1024*1024*2  =  2097152
  u16* q_bf    = (u16*)(ws + 25165824);     // 64*2048*64*2 = 16777216
  u16* k_bf    = (u16*)(ws + 41943040);
  u16* vt_bf   = (u16*)(ws + 58720256);     // V^T: [bh][64][2048]
  u16* a_bf    = (u16*)(ws + 75497472);     // attn out, [b][n][dim] bf16

  cast_kernel<<<dim3(MTOK*DIM_/4/256), 256, 0, stream>>>(x, x_bf, MTOK*DIM_/4);
  cast_kernel<<<dim3(3*DIM_*DIM_/4/256), 256, 0, stream>>>(wqkv, wqkv_bf, 3*DIM_*DIM_/4);
  cast_kernel<<<dim3(DIM_*DIM_/4/256), 256, 0, stream>>>(wout, wout_bf, DIM_*DIM_/4);

  gemm_bt<0><<<dim3(3*DIM_/128, MTOK/128), 256, 0, stream>>>(
      x_bf, wqkv_bf, DIM_, q_bf, k_bf, vt_bf, nullptr);
  attn_kernel<<<dim3(SEQ/64, BATCH*NH), 256, 0, stream>>>(q_bf, k_bf, vt_bf, a_bf);
  gemm_bt<1><<<dim3(DIM_/128, MTOK/128), 256, 0, stream>>>(
      a_bf, wout_bf, DIM_, nullptr, nullptr, nullptr, out);
}